// Round 2
// baseline (1520.108 us; speedup 1.0000x reference)
//
#include <hip/hip_runtime.h>
#include <hip/hip_bf16.h>
#include <cstddef>

typedef float f32x4 __attribute__((ext_vector_type(4)));
typedef short s16x8 __attribute__((ext_vector_type(8)));
typedef short s16x4 __attribute__((ext_vector_type(4)));

__device__ __forceinline__ short f2b(float f) {
    __hip_bfloat16 h = __float2bfloat16(f);
    return __builtin_bit_cast(short, h);
}

__device__ __forceinline__ void ldg_lds16(const short* g, short* l) {
    __builtin_amdgcn_global_load_lds(
        (const __attribute__((address_space(1))) unsigned int*)g,
        (__attribute__((address_space(3))) unsigned int*)l,
        16, 0, 0);
}

// XCD-aware bijective block swizzle (T1, m157/m204). REQUIRES nwg % 8 == 0.
// Maps dispatch-linear id so each XCD gets a contiguous chunk of tile space
// (bm fastest -> chunk shares B-panels in that XCD's private L2).
__device__ __forceinline__ void xcd_swizzle(int& bm, int& bn, int& bz) {
    const int nx = gridDim.x, ny = gridDim.y;
    const int id = (int)blockIdx.x + nx * ((int)blockIdx.y + ny * (int)blockIdx.z);
    const int cpx = (nx * ny * (int)gridDim.z) >> 3;
    const int swz = (id & 7) * cpx + (id >> 3);
    bm = swz % nx;
    const int r = swz / nx;
    bn = r % ny;
    bz = r / ny;
}

// ---------------- fp32 -> bf16 convert (vectorized, 8 elems/thread) -------------
__global__ void __launch_bounds__(256) cvt_kernel(const float* __restrict__ in,
                                                  short* __restrict__ out, long n) {
    long i = ((long)blockIdx.x * 256 + threadIdx.x) * 8;
    if (i >= n) return;
    f32x4 a = *(const f32x4*)&in[i];
    f32x4 b = *(const f32x4*)&in[i + 4];
    s16x8 r;
#pragma unroll
    for (int j = 0; j < 4; ++j) { r[j] = f2b(a[j]); r[4 + j] = f2b(b[j]); }
    *(s16x8*)&out[i] = r;
}

// ---------------- B^T-layout bf16 MFMA GEMM, 128x128 tile, BK=32 ----------------
// C[m][n] = sum_k A[m][k] * B[n][k]   (both row-major with K inner)
// MODE 0: +bias, write q->qT[col][row], k->kT[col-2048][row], v->vN[row][col-4096] (bf16)
// MODE 1: write fp32 partial (split-K z): outF + z*2048*2048, scaled
// MODE 2: write bf16 outB row-major [M][16384]
// MODE 3: +bias, write fp32 outF row-major [M][2048]
template <int MODE>
__global__ void __launch_bounds__(256)
gemm_bt(const short* __restrict__ A, const short* __restrict__ B,
        const float* __restrict__ bias, float scale,
        float* __restrict__ outF, short* __restrict__ outB,
        short* __restrict__ qT, short* __restrict__ kT, short* __restrict__ vN,
        int K) {
    __shared__ short As[128 * 32];
    __shared__ short Bs[128 * 32];

    const int tid = threadIdx.x;
    int bm, bn, bz;
    xcd_swizzle(bm, bn, bz);
    const int kChunk = (MODE == 1) ? (K >> 2) : K;
    const int kBeg = (MODE == 1) ? (bz * kChunk) : 0;

    const short* gA = A + (size_t)(bm * 128 + (tid >> 2)) * K + kBeg + (tid & 3) * 8;
    const short* gB = B + (size_t)(bn * 128 + (tid >> 2)) * K + kBeg + (tid & 3) * 8;

    f32x4 acc[4][4] = {};

    const int lane = tid & 63, wave = tid >> 6;
    const int wr = (wave >> 1) * 64, wc = (wave & 1) * 64;
    const int fr = lane & 15, fk = (lane >> 4) * 8;
    const int aoff = (wr + fr) * 32 + fk;
    const int boff = (wc + fr) * 32 + fk;

    for (int k0 = 0; k0 < kChunk; k0 += 32) {
        __syncthreads();
        ldg_lds16(gA, &As[tid * 8]);
        ldg_lds16(gA + (size_t)64 * K, &As[2048 + tid * 8]);
        ldg_lds16(gB, &Bs[tid * 8]);
        ldg_lds16(gB + (size_t)64 * K, &Bs[2048 + tid * 8]);
        gA += 32; gB += 32;
        __syncthreads();
        s16x8 af[4], bg[4];
#pragma unroll
        for (int i = 0; i < 4; ++i) af[i] = *(const s16x8*)&As[aoff + i * 512];
#pragma unroll
        for (int i = 0; i < 4; ++i) bg[i] = *(const s16x8*)&Bs[boff + i * 512];
#pragma unroll
        for (int mi = 0; mi < 4; ++mi)
#pragma unroll
            for (int ni = 0; ni < 4; ++ni)
                acc[mi][ni] = __builtin_amdgcn_mfma_f32_16x16x32_bf16(
                    af[mi], bg[ni], acc[mi][ni], 0, 0, 0);
    }

    // epilogue. C/D frag: col = lane&15, row = (lane>>4)*4 + reg  [m89/m91]
    const int rowBase = bm * 128 + wr + (lane >> 4) * 4;
    const int colBase = bn * 128 + wc + fr;
#pragma unroll
    for (int mi = 0; mi < 4; ++mi) {
#pragma unroll
        for (int ni = 0; ni < 4; ++ni) {
            const int row0 = rowBase + mi * 16;
            const int colg = colBase + ni * 16;
            f32x4 c = acc[mi][ni];
            if constexpr (MODE == 0) {
                const float bv = bias[colg];
                s16x4 p;
#pragma unroll
                for (int r = 0; r < 4; ++r) p[r] = f2b(c[r] + bv);
                if (colg < 2048) {
                    *(s16x4*)&qT[(size_t)colg * 16384 + row0] = p;
                } else if (colg < 4096) {
                    *(s16x4*)&kT[(size_t)(colg - 2048) * 16384 + row0] = p;
                } else {
#pragma unroll
                    for (int r = 0; r < 4; ++r)
                        vN[(size_t)(row0 + r) * 2048 + (colg - 4096)] = p[r];
                }
            } else if constexpr (MODE == 1) {
                float* o = outF + (size_t)bz * 4194304;
#pragma unroll
                for (int r = 0; r < 4; ++r)
                    o[(size_t)(row0 + r) * 2048 + colg] = c[r] * scale;
            } else if constexpr (MODE == 2) {
#pragma unroll
                for (int r = 0; r < 4; ++r)
                    outB[(size_t)(row0 + r) * 16384 + colg] = f2b(c[r]);
            } else {
                const float bv = bias[colg];
#pragma unroll
                for (int r = 0; r < 4; ++r)
                    outF[(size_t)(row0 + r) * 2048 + colg] = c[r] + bv;
            }
        }
    }
}

// --------- fused split-K reduce + row softmax; writes fp32 attn (output 2) + bf16 attn ----------
__global__ void __launch_bounds__(256) softmax_kernel(const float* __restrict__ part,
                                                      float* __restrict__ attnF,
                                                      short* __restrict__ attnB) {
    const int row = blockIdx.x, tid = threadIdx.x;
    const int lane = tid & 63, wave = tid >> 6;
    const size_t base = (size_t)row * 2048 + tid * 8;

    f32x4 v0 = {}, v1 = {};
#pragma unroll
    for (int p = 0; p < 4; ++p) {
        const float* pp = part + (size_t)p * 4194304 + base;
        v0 += *(const f32x4*)pp;
        v1 += *(const f32x4*)(pp + 4);
    }
    float m = -1e30f;
#pragma unroll
    for (int j = 0; j < 4; ++j) { m = fmaxf(m, v0[j]); m = fmaxf(m, v1[j]); }
#pragma unroll
    for (int o = 32; o; o >>= 1) m = fmaxf(m, __shfl_xor(m, o));
    __shared__ float red[8];
    if (lane == 0) red[wave] = m;
    __syncthreads();
    m = fmaxf(fmaxf(red[0], red[1]), fmaxf(red[2], red[3]));

    float s = 0.f;
#pragma unroll
    for (int j = 0; j < 4; ++j) {
        v0[j] = expf(v0[j] - m); s += v0[j];
        v1[j] = expf(v1[j] - m); s += v1[j];
    }
#pragma unroll
    for (int o = 32; o; o >>= 1) s += __shfl_xor(s, o);
    if (lane == 0) red[4 + wave] = s;
    __syncthreads();
    s = red[4] + red[5] + red[6] + red[7];
    const float inv = 1.0f / s;

    s16x8 r;
#pragma unroll
    for (int j = 0; j < 4; ++j) {
        v0[j] *= inv; v1[j] *= inv;
        r[j] = f2b(v0[j]); r[4 + j] = f2b(v1[j]);
    }
    *(f32x4*)&attnF[base] = v0;
    *(f32x4*)&attnF[base + 4] = v1;
    *(s16x8*)&attnB[base] = r;
}

extern "C" void kernel_launch(void* const* d_in, const int* in_sizes, int n_in,
                              void* d_out, int out_size, void* d_ws, size_t ws_size,
                              hipStream_t stream) {
    const float* x    = (const float*)d_in[0];  // [16384, 2048]
    const float* Wqkv = (const float*)d_in[1];  // [6144, 2048]
    const float* bqkv = (const float*)d_in[2];  // [6144]
    const float* Wout = (const float*)d_in[3];  // [2048, 2048]
    const float* bout = (const float*)d_in[4];  // [2048]

    float* outMain = (float*)d_out;             // 16384*2048 fp32
    float* attnF   = outMain + 33554432;        // 2048*2048 fp32

    char* ws = (char*)d_ws;
    const size_t MiB = 1ull << 20;
    short* qT    = (short*)(ws);                // 64 MiB  qT[2048][16384]
    short* kT    = (short*)(ws + 64 * MiB);     // 64 MiB
    short* vN    = (short*)(ws + 128 * MiB);    // 64 MiB  v[16384][2048]
    short* xbf   = (short*)(ws + 192 * MiB);    // 64 MiB (then: partials, then out2)
    float* part  = (float*)(ws + 192 * MiB);    // 4 x 16 MiB fp32 partials
    short* out2  = (short*)(ws + 192 * MiB);    // 64 MiB bf16 [2048][16384]
    short* wqb   = (short*)(ws + 256 * MiB);    // 24 MiB (then: attnB)
    short* attnB = (short*)(ws + 256 * MiB);    // 8 MiB
    short* wob   = (short*)(ws + 280 * MiB);    // 8 MiB
    (void)in_sizes; (void)n_in; (void)out_size; (void)ws_size;

    // converts
    cvt_kernel<<<16384, 256, 0, stream>>>(x, xbf, 33554432L);
    cvt_kernel<<<6144, 256, 0, stream>>>(Wqkv, wqb, 12582912L);
    cvt_kernel<<<2048, 256, 0, stream>>>(Wout, wob, 4194304L);

    // GEMM1: qkv = x @ Wqkv^T + b, scatter to qT/kT/v   (6144 wg, %8==0)
    gemm_bt<0><<<dim3(128, 48, 1), 256, 0, stream>>>(
        xbf, wqb, bqkv, 1.f, nullptr, nullptr, qT, kT, vN, 2048);
    // GEMM2: S = qT @ kT^T * (1/128), split-K=4 partials (1024 wg, %8==0)
    gemm_bt<1><<<dim3(16, 16, 4), 256, 0, stream>>>(
        qT, kT, nullptr, 0.0078125f, part, nullptr, nullptr, nullptr, nullptr, 16384);
    // reduce + softmax -> attn fp32 (output 2) + attn bf16
    softmax_kernel<<<2048, 256, 0, stream>>>(part, attnF, attnB);
    // GEMM3: out2 = attn @ v^T -> bf16 [2048][16384] (== out3 [16384][2048] flat) (2048 wg)
    gemm_bt<2><<<dim3(16, 128, 1), 256, 0, stream>>>(
        attnB, vN, nullptr, 1.f, nullptr, out2, nullptr, nullptr, nullptr, 2048);
    // GEMM4: final = out3 @ Wout^T + b -> d_out fp32 (2048 wg)
    gemm_bt<3><<<dim3(128, 16, 1), 256, 0, stream>>>(
        out2, wob, bout, 1.f, outMain, nullptr, nullptr, nullptr, nullptr, 2048);
}